// Round 1
// baseline (270.481 us; speedup 1.0000x reference)
//
#include <hip/hip_runtime.h>
#include <hip/hip_bf16.h>

// WindowEmbedding forward: out[b,t, w*D+d] = (t-w>=0) ? in[b, t-w, d] : 0
// B=16, T=2048, D=256, W=7 (fixed by setup_inputs).
// Pure data movement, fp32. One thread per output float4, coalesced.

constexpr int B = 16;
constexpr int T = 2048;
constexpr int D = 256;
constexpr int W = 7;
constexpr int D4 = D / 4;          // 64 float4 per (b,t,w) segment = one wave
constexpr int ROW4 = W * D4;       // 448 float4 per output row (b,t)

__global__ __launch_bounds__(256) void window_embed_kernel(
    const float4* __restrict__ in, float4* __restrict__ out, int total4) {
  int i = blockIdx.x * blockDim.x + threadIdx.x;
  if (i >= total4) return;

  // i = ((b*T + t) * W + w) * D4 + dd
  int row = i / ROW4;              // b*T + t
  int rem = i - row * ROW4;
  int w   = rem / D4;
  int dd  = rem - w * D4;
  int t   = row & (T - 1);         // T is pow2

  float4 v = make_float4(0.f, 0.f, 0.f, 0.f);
  int src_t = t - w;
  if (src_t >= 0) {
    // (b*T + src_t) = row - w
    v = in[(row - w) * D4 + dd];
  }
  out[i] = v;
}

extern "C" void kernel_launch(void* const* d_in, const int* in_sizes, int n_in,
                              void* d_out, int out_size, void* d_ws, size_t ws_size,
                              hipStream_t stream) {
  const float4* in = (const float4*)d_in[0];
  float4* out = (float4*)d_out;
  int total4 = out_size / 4;       // B*T*W*D4 = 14,680,064
  int block = 256;
  int grid = (total4 + block - 1) / block;
  window_embed_kernel<<<grid, block, 0, stream>>>(in, out, total4);
}

// Round 2
// 262.415 us; speedup vs baseline: 1.0307x; 1.0307x over previous
//
#include <hip/hip_runtime.h>
#include <hip/hip_bf16.h>

// WindowEmbedding forward: out[b,t, w*D+d] = (t-w>=0) ? in[b, t-w, d] : 0
// B=16, T=2048, D=256, W=7 (fixed by setup_inputs).
//
// Input-centric scatter: each thread loads ONE input float4 and stores it to
// the up-to-7 output slots that reference it (out row t+w, segment w). Stores
// are independent (no load->store->load chains), so the write stream runs at
// fill-kernel rates (~6.5 TB/s measured on this chip) instead of being
// latency-bound like the round-0 gather (1 load -> 1 dependent store, 1 TB/s).
// Input is read exactly once (34 MB instead of 7x235 MB through L2).

constexpr int B  = 16;
constexpr int T  = 2048;
constexpr int D  = 256;
constexpr int W  = 7;
constexpr int D4 = D / 4;            // 64 float4 per (b,t,w) segment = 1 wave
constexpr int ROW4 = W * D4;         // 448 float4 per output row

__global__ __launch_bounds__(256) void window_scatter_kernel(
    const float4* __restrict__ in, float4* __restrict__ out) {
  int i = blockIdx.x * 256 + threadIdx.x;   // input float4 index, total B*T*D4
  int row = i >> 6;                         // b*T + t
  int dd  = i & 63;
  int t   = row & (T - 1);                  // T is pow2

  float4 v = in[i];
  // out index for slot w: ((row + w) * ROW4) + w*D4 + dd = base + w*(ROW4+D4)
  int base = row * ROW4 + dd;
#pragma unroll
  for (int w = 0; w < W; ++w) {
    if (t + w < T) {                        // wave-uniform branch
      out[base + w * (ROW4 + D4)] = v;
    }
  }
}

// Output slots (t, w) with t < w are never produced by the scatter: zero them.
// 21 (w,t) pairs per batch x 64 float4 = 21504 threads total (344 KB).
__global__ __launch_bounds__(256) void window_zero_edges_kernel(float4* __restrict__ out) {
  int j = blockIdx.x * 256 + threadIdx.x;
  if (j >= B * 21 * 64) return;
  int dd = j & 63;
  int p  = (j >> 6) % 21;
  int b  = j / (21 * 64);
  // enumeration of (w, t) with 1 <= w <= 6, 0 <= t < w
  const unsigned char wv[21] = {1,2,2,3,3,3,4,4,4,4,5,5,5,5,5,6,6,6,6,6,6};
  const unsigned char tv[21] = {0,0,1,0,1,2,0,1,2,3,0,1,2,3,4,0,1,2,3,4,5};
  int w = wv[p], t = tv[p];
  out[((b * T + t) * W + w) * D4 + dd] = make_float4(0.f, 0.f, 0.f, 0.f);
}

extern "C" void kernel_launch(void* const* d_in, const int* in_sizes, int n_in,
                              void* d_out, int out_size, void* d_ws, size_t ws_size,
                              hipStream_t stream) {
  const float4* in = (const float4*)d_in[0];
  float4* out = (float4*)d_out;

  int total_in4 = B * T * D4;               // 2,097,152
  window_scatter_kernel<<<total_in4 / 256, 256, 0, stream>>>(in, out);

  int nz = B * 21 * 64;                     // 21,504
  window_zero_edges_kernel<<<(nz + 255) / 256, 256, 0, stream>>>(out);
}

// Round 4
// 256.498 us; speedup vs baseline: 1.0545x; 1.0231x over previous
//
#include <hip/hip_runtime.h>
#include <hip/hip_bf16.h>

// WindowEmbedding forward: out[b,t, w*D+d] = (t-w>=0) ? in[b, t-w, d] : 0
// B=16, T=2048, D=256, W=7.
//
// Input-centric scatter, single fused kernel:
//  - each thread loads ONE input vec4 (input read exactly once: 34 MB)
//  - stores it to the up-to-7 output slots referencing it (235 MB writes)
//  - threads on rows t<6 also zero the never-written slots (w>t) of their
//    own row (replaces the separate edge kernel).
// All output stores are non-temporal: output is never re-read, so bypass
// L2 write-allocate (don't cycle 235 MB through the 32 MB aggregate L2
// while the input read stream lives there).
//
// Note: __builtin_nontemporal_store requires a clang vector type, not HIP's
// float4 class — use ext_vector_type(4) float (identical 16 B layout).

typedef float vf4 __attribute__((ext_vector_type(4)));

constexpr int B  = 16;
constexpr int T  = 2048;
constexpr int D  = 256;
constexpr int W  = 7;
constexpr int D4 = D / 4;            // 64 vec4 per (b,t,w) segment = 1 wave
constexpr int ROW4 = W * D4;         // 448 vec4 per output row

__global__ __launch_bounds__(256) void window_scatter_fused_kernel(
    const vf4* __restrict__ in, vf4* __restrict__ out) {
  int i = blockIdx.x * 256 + threadIdx.x;   // input vec4 index, B*T*D4 total
  int row = i >> 6;                         // b*T + t
  int dd  = i & 63;
  int t   = row & (T - 1);                  // T is pow2

  vf4 v = in[i];
  int base = row * ROW4 + dd;

  // scatter: out[(row+w)*ROW4 + w*D4 + dd] = base + w*(ROW4+D4)
#pragma unroll
  for (int w = 0; w < W; ++w) {
    if (t + w < T) {                        // wave-uniform
      __builtin_nontemporal_store(v, &out[base + w * (ROW4 + D4)]);
    }
  }

  // edge zeros: slots (t, w) with w > t are never produced by any scatter.
  // Only rows t<6 diverge here (6 rows of 2048 per batch).
  if (t < W - 1) {
    vf4 z = {0.f, 0.f, 0.f, 0.f};
    for (int w = t + 1; w < W; ++w) {
      __builtin_nontemporal_store(z, &out[base + w * D4]);
    }
  }
}

extern "C" void kernel_launch(void* const* d_in, const int* in_sizes, int n_in,
                              void* d_out, int out_size, void* d_ws, size_t ws_size,
                              hipStream_t stream) {
  const vf4* in = (const vf4*)d_in[0];
  vf4* out = (vf4*)d_out;
  int total_in4 = B * T * D4;               // 2,097,152
  window_scatter_fused_kernel<<<total_in4 / 256, 256, 0, stream>>>(in, out);
}